// Round 8
// baseline (1743.024 us; speedup 1.0000x reference)
//
#include <hip/hip_runtime.h>
#include <hip/hip_bf16.h>
#include <cstdint>

#define N_PROT 19000
#define N_DRUGS 4200
#define BATCH 8192
#define D0 1024
#define D1 512
#define D2 128
#define NROWS (2 * BATCH)  // 16384 MLP rows, interleaved: r = 2*i + s
#define MAXNNZ 192         // Binomial(19000,0.002): mean 38, sd 6.2 — >20 sigma
#define NCHUNK 8           // gather column chunks (one per XCD)
#define CCOLS (D0 / NCHUNK)

// DIAGNOSTIC round: repeat each kernel so every stage exceeds the ~190us
// harness poison-fills and surfaces in rocprof top-5 with its counters.
// All rep loops are idempotent + barrier-protected. Revert next round.
#define REP_SCAN 6
#define REP_GATH 36
#define REP_BLDH 30
#define REP_GEMM1 8
#define REP_GEMM2 36

typedef __bf16 bf16_t;
typedef __bf16 bf16x8 __attribute__((ext_vector_type(8)));
typedef __bf16 bf16x4 __attribute__((ext_vector_type(4)));
typedef __bf16 bf16x2 __attribute__((ext_vector_type(2)));
typedef float f32x4 __attribute__((ext_vector_type(4)));

// async global->LDS, 16B per lane, wave-uniform LDS base + lane*16 (HW rule)
#define GLOAD_LDS16(gsrc, ldst)                                        \
  __builtin_amdgcn_global_load_lds(                                    \
      (const __attribute__((address_space(1))) void*)(gsrc),           \
      (__attribute__((address_space(3))) void*)(ldst), 16, 0, 0)

// ---------------------------------------------------------------------------
// Kernel 1: weight conversions (NO rep — pure stream, model solid ~18us).
// ---------------------------------------------------------------------------
__global__ __launch_bounds__(256) void k_convert(
    const float* __restrict__ W0, const float* __restrict__ W1,
    const float* __restrict__ W2, bf16_t* __restrict__ W0b,
    bf16_t* __restrict__ W1T, bf16_t* __restrict__ W2T)
{
  const int S = gridDim.x * 256;
  const int tid0 = blockIdx.x * 256 + threadIdx.x;
  constexpr int NV0 = N_PROT * D0 / 4;

  int v = tid0;
  for (; v + 3 * S < NV0; v += 4 * S) {
    f32x4 w0 = reinterpret_cast<const f32x4*>(W0)[v];
    f32x4 w1 = reinterpret_cast<const f32x4*>(W0)[v + S];
    f32x4 w2 = reinterpret_cast<const f32x4*>(W0)[v + 2 * S];
    f32x4 w3 = reinterpret_cast<const f32x4*>(W0)[v + 3 * S];
    bf16x4 o0 = {(bf16_t)w0[0], (bf16_t)w0[1], (bf16_t)w0[2], (bf16_t)w0[3]};
    bf16x4 o1 = {(bf16_t)w1[0], (bf16_t)w1[1], (bf16_t)w1[2], (bf16_t)w1[3]};
    bf16x4 o2 = {(bf16_t)w2[0], (bf16_t)w2[1], (bf16_t)w2[2], (bf16_t)w2[3]};
    bf16x4 o3 = {(bf16_t)w3[0], (bf16_t)w3[1], (bf16_t)w3[2], (bf16_t)w3[3]};
    reinterpret_cast<bf16x4*>(W0b)[v] = o0;
    reinterpret_cast<bf16x4*>(W0b)[v + S] = o1;
    reinterpret_cast<bf16x4*>(W0b)[v + 2 * S] = o2;
    reinterpret_cast<bf16x4*>(W0b)[v + 3 * S] = o3;
  }
  for (; v < NV0; v += S) {
    f32x4 w = reinterpret_cast<const f32x4*>(W0)[v];
    bf16x4 o = {(bf16_t)w[0], (bf16_t)w[1], (bf16_t)w[2], (bf16_t)w[3]};
    reinterpret_cast<bf16x4*>(W0b)[v] = o;
  }
  for (int idx = tid0; idx < D0 * D1; idx += S) {   // idx = n*D0 + k
    const int n = idx >> 10, k = idx & (D0 - 1);
    W1T[idx] = (bf16_t)W1[(size_t)k * D1 + n];
  }
  for (int idx = tid0; idx < D1 * D2; idx += S) {   // idx = n*D1 + k
    const int n = idx >> 9, k = idx & (D1 - 1);
    W2T[idx] = (bf16_t)W2[(size_t)k * D2 + n];
  }
}

// ---------------------------------------------------------------------------
// Kernel 2: scan table rows -> per-drug nonzero index lists. REP_SCAN x.
// ---------------------------------------------------------------------------
__global__ __launch_bounds__(256) void k_scan(
    const uint32_t* __restrict__ table_u, int* __restrict__ g_cnt,
    int* __restrict__ g_idx)
{
  __shared__ int s_idx[MAXNNZ];
  __shared__ int s_cnt;
  const int d = blockIdx.x;
  const uint4* row = reinterpret_cast<const uint4*>(table_u + (size_t)d * N_PROT);
  constexpr int NQ = N_PROT / 4;  // 4750

#define SCAN_BODY(v, qq)                                                        \
  if ((v).x | (v).y | (v).z | (v).w) {                                          \
    if ((v).x) { int k = atomicAdd(&s_cnt, 1); if (k < MAXNNZ) s_idx[k] = 4 * (qq) + 0; } \
    if ((v).y) { int k = atomicAdd(&s_cnt, 1); if (k < MAXNNZ) s_idx[k] = 4 * (qq) + 1; } \
    if ((v).z) { int k = atomicAdd(&s_cnt, 1); if (k < MAXNNZ) s_idx[k] = 4 * (qq) + 2; } \
    if ((v).w) { int k = atomicAdd(&s_cnt, 1); if (k < MAXNNZ) s_idx[k] = 4 * (qq) + 3; } \
  }

  for (int rep = 0; rep < REP_SCAN; ++rep) {
    __syncthreads();                  // prior rep done reading s_idx/s_cnt
    if (threadIdx.x == 0) s_cnt = 0;
    __syncthreads();

    int q = threadIdx.x;
    for (; q + 256 < NQ; q += 512) {
      uint4 v0 = row[q];
      uint4 v1 = row[q + 256];
      SCAN_BODY(v0, q)
      SCAN_BODY(v1, q + 256)
    }
    for (; q < NQ; q += 256) {
      uint4 v = row[q];
      SCAN_BODY(v, q)
    }

    __syncthreads();
    const int n = min(s_cnt, MAXNNZ);
    if (threadIdx.x == 0) g_cnt[d] = n;
    for (int t = threadIdx.x; t < n; t += 256) g_idx[(size_t)d * MAXNNZ + t] = s_idx[t];
  }
#undef SCAN_BODY
}

// ---------------------------------------------------------------------------
// Kernel 3: XCD-chunked gather. h0[d][:] = sum of listed W0b rows + b0. REP x.
// ---------------------------------------------------------------------------
__global__ __launch_bounds__(64) void k_gather(
    const bf16_t* __restrict__ W0b, const int* __restrict__ g_cnt,
    const int* __restrict__ g_idx, const float* __restrict__ b0,
    float* __restrict__ h0)
{
  __shared__ int s_idx[MAXNNZ];
  const int chunk = blockIdx.x & (NCHUNK - 1);
  const int d = blockIdx.x >> 3;
  const int n = g_cnt[d];
  for (int t = threadIdx.x; t < n; t += 64) s_idx[t] = g_idx[(size_t)d * MAXNNZ + t];
  __syncthreads();

  const int col = chunk * CCOLS + threadIdx.x * 2;
  const float bb0 = b0[col], bb1 = b0[col + 1];

  for (int rep = 0; rep < REP_GATH; ++rep) {
    float c0 = 0.f, c1 = 0.f, d0_ = 0.f, d1_ = 0.f;
    float e0 = 0.f, e1 = 0.f, f0 = 0.f, f1 = 0.f;
    int t = 0;
    for (; t + 4 <= n; t += 4) {
      bf16x2 w0 = *reinterpret_cast<const bf16x2*>(W0b + (size_t)s_idx[t] * D0 + col);
      bf16x2 w1 = *reinterpret_cast<const bf16x2*>(W0b + (size_t)s_idx[t + 1] * D0 + col);
      bf16x2 w2 = *reinterpret_cast<const bf16x2*>(W0b + (size_t)s_idx[t + 2] * D0 + col);
      bf16x2 w3 = *reinterpret_cast<const bf16x2*>(W0b + (size_t)s_idx[t + 3] * D0 + col);
      c0 += (float)w0[0]; c1 += (float)w0[1];
      d0_ += (float)w1[0]; d1_ += (float)w1[1];
      e0 += (float)w2[0]; e1 += (float)w2[1];
      f0 += (float)w3[0]; f1 += (float)w3[1];
    }
    for (; t < n; ++t) {
      bf16x2 w = *reinterpret_cast<const bf16x2*>(W0b + (size_t)s_idx[t] * D0 + col);
      c0 += (float)w[0]; c1 += (float)w[1];
    }
    float2 o;
    o.x = ((c0 + d0_) + (e0 + f0)) + bb0;
    o.y = ((c1 + d1_) + (e1 + f1)) + bb1;
    *reinterpret_cast<float2*>(h0 + (size_t)d * D0 + col) = o;
  }
}

// ---------------------------------------------------------------------------
// Kernel 4: H[r][:] = relu(h0[drug(r)] + c(r)*W0_last), bf16. REP x.
// ---------------------------------------------------------------------------
__global__ __launch_bounds__(256) void k_build_H(
    const float* __restrict__ h0, const int* __restrict__ pairs,
    const float* __restrict__ conc, const float* __restrict__ W0last,
    bf16_t* __restrict__ H)
{
  const int r = blockIdx.x;
  const int drug = pairs[r];
  const float c = conc[3 * (r >> 1) + 1 + (r & 1)];
  const int j = threadIdx.x * 4;

  for (int rep = 0; rep < REP_BLDH; ++rep) {
    float4 hv = *reinterpret_cast<const float4*>(h0 + (size_t)drug * D0 + j);
    float4 wl = *reinterpret_cast<const float4*>(W0last + j);
    bf16x4 o;
    o[0] = (bf16_t)fmaxf(hv.x + c * wl.x, 0.f);
    o[1] = (bf16_t)fmaxf(hv.y + c * wl.y, 0.f);
    o[2] = (bf16_t)fmaxf(hv.z + c * wl.z, 0.f);
    o[3] = (bf16_t)fmaxf(hv.w + c * wl.w, 0.f);
    *reinterpret_cast<bf16x4*>(H + (size_t)r * D0 + j) = o;
  }
}

// ---------------------------------------------------------------------------
// Kernel 5: m97-style GEMM1. H1 = relu(H @ W1 + b1). 128x128 tile, BK=32,
// global_load_lds width-16 staging, double-buffered linear LDS. REP x.
// ---------------------------------------------------------------------------
__global__ __launch_bounds__(256) void k_gemm1(
    const bf16_t* __restrict__ A, const bf16_t* __restrict__ BT,
    const float* __restrict__ bias, bf16_t* __restrict__ C)
{
  constexpr int K = D0;       // 1024
  constexpr int N = D1;       // 512
  constexpr int NT = K / 32;  // 32 K-steps
  __shared__ bf16_t sA[2][128 * 32];
  __shared__ bf16_t sB[2][128 * 32];

  const int tid = threadIdx.x;
  const int w = tid >> 6;
  const int lane = tid & 63;
  const int wr = w >> 1, wc = w & 1;
  const int row0 = blockIdx.x * 128;
  const int col0 = blockIdx.y * 128;
  const int fr = lane & 15;
  const int q = lane >> 4;

  const int srow0 = (w * 2 + 0) * 16 + (lane >> 2);
  const int srow1 = (w * 2 + 1) * 16 + (lane >> 2);
  const int skel = (lane & 3) * 8;
  const bf16_t* a_src0 = A + (size_t)(row0 + srow0) * K + skel;
  const bf16_t* a_src1 = A + (size_t)(row0 + srow1) * K + skel;
  const bf16_t* b_src0 = BT + (size_t)(col0 + srow0) * K + skel;
  const bf16_t* b_src1 = BT + (size_t)(col0 + srow1) * K + skel;
  const int ldst0 = (w * 2 + 0) * 512;
  const int ldst1 = (w * 2 + 1) * 512;

  auto stage = [&](int buf, int k0) {
    GLOAD_LDS16(a_src0 + k0, &sA[buf][ldst0]);
    GLOAD_LDS16(a_src1 + k0, &sA[buf][ldst1]);
    GLOAD_LDS16(b_src0 + k0, &sB[buf][ldst0]);
    GLOAD_LDS16(b_src1 + k0, &sB[buf][ldst1]);
  };

  for (int rep = 0; rep < REP_GEMM1; ++rep) {
    f32x4 acc[4][4] = {};
    __syncthreads();          // rep boundary: LDS reuse protection
    stage(0, 0);
    for (int ks = 0; ks < NT; ++ks) {
      const int buf = ks & 1;
      __syncthreads();
      if (ks + 1 < NT) stage(buf ^ 1, (ks + 1) * 32);

      bf16x8 a[4], b[4];
#pragma unroll
      for (int m = 0; m < 4; ++m)
        a[m] = *reinterpret_cast<const bf16x8*>(&sA[buf][(wr * 64 + m * 16 + fr) * 32 + q * 8]);
#pragma unroll
      for (int n = 0; n < 4; ++n)
        b[n] = *reinterpret_cast<const bf16x8*>(&sB[buf][(wc * 64 + n * 16 + fr) * 32 + q * 8]);
#pragma unroll
      for (int m = 0; m < 4; ++m)
#pragma unroll
        for (int n = 0; n < 4; ++n)
          acc[m][n] = __builtin_amdgcn_mfma_f32_16x16x32_bf16(a[m], b[n], acc[m][n], 0, 0, 0);
    }

#pragma unroll
    for (int m = 0; m < 4; ++m)
#pragma unroll
      for (int n = 0; n < 4; ++n) {
        const int col = col0 + wc * 64 + n * 16 + fr;
        const float bb = bias[col];
#pragma unroll
        for (int r = 0; r < 4; ++r) {
          const int row = row0 + wr * 64 + m * 16 + 4 * q + r;
          C[(size_t)row * N + col] = (bf16_t)fmaxf(acc[m][n][r] + bb, 0.f);
        }
      }
  }
}

// ---------------------------------------------------------------------------
// Kernel 6: gemm2 fused with the pair-dot. REP x.
// ---------------------------------------------------------------------------
__global__ __launch_bounds__(256) void k_gemm2_dot(
    const bf16_t* __restrict__ A, const bf16_t* __restrict__ BT,
    const float* __restrict__ bias, float* __restrict__ out)
{
  __shared__ float red[2][64];
  const int wid = threadIdx.x >> 6;
  const int lane = threadIdx.x & 63;
  const int wr = wid >> 1, wc = wid & 1;
  const int row0 = blockIdx.x * 128 + wr * 64;
  const int col0 = wc * 64;
  const int fr = lane & 15;
  const int fk = (lane >> 4) * 8;
  constexpr int K = D1;

  for (int rep = 0; rep < REP_GEMM2; ++rep) {
    __syncthreads();          // rep boundary: red[] reuse protection
    f32x4 acc[4][4] = {};
#pragma unroll 2
    for (int k0 = 0; k0 < K; k0 += 32) {
      bf16x8 a[4], b[4];
#pragma unroll
      for (int m = 0; m < 4; ++m)
        a[m] = *reinterpret_cast<const bf16x8*>(A + (size_t)(row0 + m * 16 + fr) * K + k0 + fk);
#pragma unroll
      for (int n = 0; n < 4; ++n)
        b[n] = *reinterpret_cast<const bf16x8*>(BT + (size_t)(col0 + n * 16 + fr) * K + k0 + fk);
#pragma unroll
      for (int m = 0; m < 4; ++m)
#pragma unroll
        for (int n = 0; n < 4; ++n)
          acc[m][n] = __builtin_amdgcn_mfma_f32_16x16x32_bf16(a[m], b[n], acc[m][n], 0, 0, 0);
    }

    const int cc = lane & 15;
#pragma unroll
    for (int m = 0; m < 4; ++m) {
      float sA = 0.f, sB = 0.f;
#pragma unroll
      for (int n = 0; n < 4; ++n) {
        const float bb = bias[col0 + n * 16 + cc];
        const float v0 = acc[m][n][0] + bb;
        const float v1 = acc[m][n][1] + bb;
        const float v2 = acc[m][n][2] + bb;
        const float v3 = acc[m][n][3] + bb;
        sA += v0 * v1;
        sB += v2 * v3;
      }
#pragma unroll
      for (int off = 8; off >= 1; off >>= 1) {
        sA += __shfl_xor(sA, off);
        sB += __shfl_xor(sB, off);
      }
      if (cc == 0) {
        const int p = wr * 32 + m * 8 + 2 * (lane >> 4);
        red[wc][p] = sA;
        red[wc][p + 1] = sB;
      }
    }
    __syncthreads();
    if (threadIdx.x < 64)
      out[blockIdx.x * 64 + threadIdx.x] = red[0][threadIdx.x] + red[1][threadIdx.x];
  }
}

extern "C" void kernel_launch(void* const* d_in, const int* in_sizes, int n_in,
                              void* d_out, int out_size, void* d_ws, size_t ws_size,
                              hipStream_t stream) {
  const float* table = (const float*)d_in[0];
  const int*   pairs = (const int*)d_in[1];
  const float* conc  = (const float*)d_in[2];
  const float* W0    = (const float*)d_in[3];
  const float* b0    = (const float*)d_in[4];
  const float* W1    = (const float*)d_in[5];
  const float* b1    = (const float*)d_in[6];
  const float* W2    = (const float*)d_in[7];
  const float* b2    = (const float*)d_in[8];
  float* out = (float*)d_out;

  char* ws = (char*)d_ws;
  float*  h0  = (float*)ws;  ws += (size_t)N_DRUGS * D0 * sizeof(float);    // 17.2 MB
  bf16_t* W0b = (bf16_t*)ws; ws += (size_t)N_PROT * D0 * sizeof(bf16_t);    // 38.9 MB
  bf16_t* W1T = (bf16_t*)ws; ws += (size_t)D1 * D0 * sizeof(bf16_t);        //  1.0 MB
  bf16_t* W2T = (bf16_t*)ws; ws += (size_t)D2 * D1 * sizeof(bf16_t);        //  0.13 MB
  bf16_t* H   = (bf16_t*)ws; ws += (size_t)NROWS * D0 * sizeof(bf16_t);     // 33.6 MB
  bf16_t* H1  = (bf16_t*)ws; ws += (size_t)NROWS * D1 * sizeof(bf16_t);     // 16.8 MB
  int* g_idx = (int*)ws;     ws += (size_t)N_DRUGS * MAXNNZ * sizeof(int);  //  3.2 MB
  int* g_cnt = (int*)ws;     ws += (size_t)N_DRUGS * sizeof(int);           // 16.8 KB

  k_convert<<<2048, 256, 0, stream>>>(W0, W1, W2, W0b, W1T, W2T);
  k_scan<<<N_DRUGS, 256, 0, stream>>>((const uint32_t*)table, g_cnt, g_idx);
  k_gather<<<N_DRUGS * NCHUNK, 64, 0, stream>>>(W0b, g_cnt, g_idx, b0, h0);
  k_build_H<<<NROWS, 256, 0, stream>>>(h0, pairs, conc, W0 + (size_t)N_PROT * D0, H);
  k_gemm1<<<dim3(NROWS / 128, D1 / 128), 256, 0, stream>>>(H, W1T, b1, H1);
  k_gemm2_dot<<<NROWS / 128, 256, 0, stream>>>(H1, W2T, b2, out);
}

// Round 9
// 471.233 us; speedup vs baseline: 3.6989x; 3.6989x over previous
//
#include <hip/hip_runtime.h>
#include <hip/hip_bf16.h>
#include <cstdint>

#define N_PROT 19000
#define N_DRUGS 4200
#define BATCH 8192
#define D0 1024
#define D1 512
#define D2 128
#define NROWS (2 * BATCH)  // 16384 MLP rows, interleaved: r = 2*i + s
#define MAXNNZ 192         // Binomial(19000,0.002): mean 38, sd 6.2 — >20 sigma

// DIAGNOSTIC: only gemm1 is REP'd this round (R8 measured gather/gemm2;
// gemm1 is the remaining big unknown, est ~66us by budget arithmetic).
#define REP_GEMM1 10

typedef __bf16 bf16_t;
typedef __bf16 bf16x8 __attribute__((ext_vector_type(8)));
typedef __bf16 bf16x4 __attribute__((ext_vector_type(4)));
typedef float f32x4 __attribute__((ext_vector_type(4)));

// async global->LDS, 16B per lane, wave-uniform LDS base + lane*16 (HW rule)
#define GLOAD_LDS16(gsrc, ldst)                                        \
  __builtin_amdgcn_global_load_lds(                                    \
      (const __attribute__((address_space(1))) void*)(gsrc),           \
      (__attribute__((address_space(3))) void*)(ldst), 16, 0, 0)

// ---------------------------------------------------------------------------
// Kernel 1: small weight conversions only (W0 no longer converted — the
// gather reads W0 f32 directly, saving the 117MB convert pass).
// W1 (1024x512) -> W1T bf16 (512x1024); W2 (512x128) -> W2T bf16 (128x512).
// ---------------------------------------------------------------------------
__global__ __launch_bounds__(256) void k_convert_w(
    const float* __restrict__ W1, const float* __restrict__ W2,
    bf16_t* __restrict__ W1T, bf16_t* __restrict__ W2T)
{
  const int idx = blockIdx.x * 256 + threadIdx.x;
  if (idx < D0 * D1) {                       // idx = n*D0 + k
    const int nn = idx >> 10, k = idx & (D0 - 1);
    W1T[idx] = (bf16_t)W1[(size_t)k * D1 + nn];
  } else {
    const int j = idx - D0 * D1;             // j = n*D1 + k
    if (j < D1 * D2) {
      const int nn = j >> 9, k = j & (D1 - 1);
      W2T[j] = (bf16_t)W2[(size_t)k * D2 + nn];
    }
  }
}

// ---------------------------------------------------------------------------
// Kernel 2: scan table rows -> per-drug nonzero index lists (R7 form).
// ---------------------------------------------------------------------------
__global__ __launch_bounds__(256) void k_scan(
    const uint32_t* __restrict__ table_u, int* __restrict__ g_cnt,
    int* __restrict__ g_idx)
{
  __shared__ int s_idx[MAXNNZ];
  __shared__ int s_cnt;
  const int d = blockIdx.x;
  if (threadIdx.x == 0) s_cnt = 0;
  __syncthreads();

  const uint4* row = reinterpret_cast<const uint4*>(table_u + (size_t)d * N_PROT);
  constexpr int NQ = N_PROT / 4;  // 4750

#define SCAN_BODY(v, qq)                                                        \
  if ((v).x | (v).y | (v).z | (v).w) {                                          \
    if ((v).x) { int k = atomicAdd(&s_cnt, 1); if (k < MAXNNZ) s_idx[k] = 4 * (qq) + 0; } \
    if ((v).y) { int k = atomicAdd(&s_cnt, 1); if (k < MAXNNZ) s_idx[k] = 4 * (qq) + 1; } \
    if ((v).z) { int k = atomicAdd(&s_cnt, 1); if (k < MAXNNZ) s_idx[k] = 4 * (qq) + 2; } \
    if ((v).w) { int k = atomicAdd(&s_cnt, 1); if (k < MAXNNZ) s_idx[k] = 4 * (qq) + 3; } \
  }

  int q = threadIdx.x;
  for (; q + 256 < NQ; q += 512) {
    uint4 v0 = row[q];
    uint4 v1 = row[q + 256];
    SCAN_BODY(v0, q)
    SCAN_BODY(v1, q + 256)
  }
  for (; q < NQ; q += 256) {
    uint4 v = row[q];
    SCAN_BODY(v, q)
  }
#undef SCAN_BODY

  __syncthreads();
  const int n = min(s_cnt, MAXNNZ);
  if (threadIdx.x == 0) g_cnt[d] = n;
  for (int t = threadIdx.x; t < n; t += 256) g_idx[(size_t)d * MAXNNZ + t] = s_idx[t];
}

// ---------------------------------------------------------------------------
// Kernel 3: gather, VALU-fixed. h0[d][:] = sum of listed W0 f32 rows + b0.
// R8 showed VALUBusy=98% (per-lane 64b addressing on 4B loads). Fix:
// readfirstlane-scalarized row base (SALU does per-row math; VMEM uses
// s[base]+voffset), f32x4 per thread (256 thr = full 1024-col row),
// unroll-4 independent accumulators. f32 gather = exact layer-0.
// ---------------------------------------------------------------------------
__global__ __launch_bounds__(256) void k_gather(
    const float* __restrict__ W0, const int* __restrict__ g_cnt,
    const int* __restrict__ g_idx, const float* __restrict__ b0,
    float* __restrict__ h0)
{
  __shared__ int s_idx[MAXNNZ];
  const int d = blockIdx.x;
  const int n = g_cnt[d];
  for (int t = threadIdx.x; t < n; t += 256) s_idx[t] = g_idx[(size_t)d * MAXNNZ + t];
  __syncthreads();

  const int j4 = threadIdx.x * 4;
  f32x4 a0 = {0.f, 0.f, 0.f, 0.f}, a1 = a0, a2 = a0, a3 = a0;
  int t = 0;
  for (; t + 4 <= n; t += 4) {
    const float* p0 = W0 + (size_t)__builtin_amdgcn_readfirstlane(s_idx[t + 0]) * D0;
    const float* p1 = W0 + (size_t)__builtin_amdgcn_readfirstlane(s_idx[t + 1]) * D0;
    const float* p2 = W0 + (size_t)__builtin_amdgcn_readfirstlane(s_idx[t + 2]) * D0;
    const float* p3 = W0 + (size_t)__builtin_amdgcn_readfirstlane(s_idx[t + 3]) * D0;
    a0 += *reinterpret_cast<const f32x4*>(p0 + j4);
    a1 += *reinterpret_cast<const f32x4*>(p1 + j4);
    a2 += *reinterpret_cast<const f32x4*>(p2 + j4);
    a3 += *reinterpret_cast<const f32x4*>(p3 + j4);
  }
  for (; t < n; ++t) {
    const float* p = W0 + (size_t)__builtin_amdgcn_readfirstlane(s_idx[t]) * D0;
    a0 += *reinterpret_cast<const f32x4*>(p + j4);
  }
  f32x4 bb = *reinterpret_cast<const f32x4*>(b0 + j4);
  f32x4 r = ((a0 + a1) + (a2 + a3)) + bb;
  *reinterpret_cast<f32x4*>(h0 + (size_t)d * D0 + j4) = r;
}

// ---------------------------------------------------------------------------
// Kernel 4: H[r][:] = relu(h0[drug(r)] + c(r)*W0_last), bf16 (b0 in h0).
// ---------------------------------------------------------------------------
__global__ __launch_bounds__(256) void k_build_H(
    const float* __restrict__ h0, const int* __restrict__ pairs,
    const float* __restrict__ conc, const float* __restrict__ W0last,
    bf16_t* __restrict__ H)
{
  const int r = blockIdx.x;
  const int drug = pairs[r];
  const float c = conc[3 * (r >> 1) + 1 + (r & 1)];

  const int j = threadIdx.x * 4;
  float4 hv = *reinterpret_cast<const float4*>(h0 + (size_t)drug * D0 + j);
  float4 wl = *reinterpret_cast<const float4*>(W0last + j);
  bf16x4 o;
  o[0] = (bf16_t)fmaxf(hv.x + c * wl.x, 0.f);
  o[1] = (bf16_t)fmaxf(hv.y + c * wl.y, 0.f);
  o[2] = (bf16_t)fmaxf(hv.z + c * wl.z, 0.f);
  o[3] = (bf16_t)fmaxf(hv.w + c * wl.w, 0.f);
  *reinterpret_cast<bf16x4*>(H + (size_t)r * D0 + j) = o;
}

// ---------------------------------------------------------------------------
// Kernel 5: m97-style GEMM1 (unchanged structure), REP x10 for attribution.
// H1 = relu(H @ W1 + b1). 128x128 tile, BK=32, global_load_lds width-16,
// double-buffered linear LDS, one barrier per K-step.
// ---------------------------------------------------------------------------
__global__ __launch_bounds__(256) void k_gemm1(
    const bf16_t* __restrict__ A, const bf16_t* __restrict__ BT,
    const float* __restrict__ bias, bf16_t* __restrict__ C)
{
  constexpr int K = D0;       // 1024
  constexpr int N = D1;       // 512
  constexpr int NT = K / 32;  // 32 K-steps
  __shared__ bf16_t sA[2][128 * 32];
  __shared__ bf16_t sB[2][128 * 32];

  const int tid = threadIdx.x;
  const int w = tid >> 6;
  const int lane = tid & 63;
  const int wr = w >> 1, wc = w & 1;
  const int row0 = blockIdx.x * 128;
  const int col0 = blockIdx.y * 128;
  const int fr = lane & 15;
  const int q = lane >> 4;

  const int srow0 = (w * 2 + 0) * 16 + (lane >> 2);
  const int srow1 = (w * 2 + 1) * 16 + (lane >> 2);
  const int skel = (lane & 3) * 8;
  const bf16_t* a_src0 = A + (size_t)(row0 + srow0) * K + skel;
  const bf16_t* a_src1 = A + (size_t)(row0 + srow1) * K + skel;
  const bf16_t* b_src0 = BT + (size_t)(col0 + srow0) * K + skel;
  const bf16_t* b_src1 = BT + (size_t)(col0 + srow1) * K + skel;
  const int ldst0 = (w * 2 + 0) * 512;
  const int ldst1 = (w * 2 + 1) * 512;

  auto stage = [&](int buf, int k0) {
    GLOAD_LDS16(a_src0 + k0, &sA[buf][ldst0]);
    GLOAD_LDS16(a_src1 + k0, &sA[buf][ldst1]);
    GLOAD_LDS16(b_src0 + k0, &sB[buf][ldst0]);
    GLOAD_LDS16(b_src1 + k0, &sB[buf][ldst1]);
  };

  for (int rep = 0; rep < REP_GEMM1; ++rep) {
    f32x4 acc[4][4] = {};
    __syncthreads();          // rep boundary: LDS reuse protection
    stage(0, 0);
    for (int ks = 0; ks < NT; ++ks) {
      const int buf = ks & 1;
      __syncthreads();
      if (ks + 1 < NT) stage(buf ^ 1, (ks + 1) * 32);

      bf16x8 a[4], b[4];
#pragma unroll
      for (int m = 0; m < 4; ++m)
        a[m] = *reinterpret_cast<const bf16x8*>(&sA[buf][(wr * 64 + m * 16 + fr) * 32 + q * 8]);
#pragma unroll
      for (int n = 0; n < 4; ++n)
        b[n] = *reinterpret_cast<const bf16x8*>(&sB[buf][(wc * 64 + n * 16 + fr) * 32 + q * 8]);
#pragma unroll
      for (int m = 0; m < 4; ++m)
#pragma unroll
        for (int n = 0; n < 4; ++n)
          acc[m][n] = __builtin_amdgcn_mfma_f32_16x16x32_bf16(a[m], b[n], acc[m][n], 0, 0, 0);
    }

#pragma unroll
    for (int m = 0; m < 4; ++m)
#pragma unroll
      for (int n = 0; n < 4; ++n) {
        const int col = col0 + wc * 64 + n * 16 + fr;
        const float bb = bias[col];
#pragma unroll
        for (int r = 0; r < 4; ++r) {
          const int row = row0 + wr * 64 + m * 16 + 4 * q + r;
          C[(size_t)row * N + col] = (bf16_t)fmaxf(acc[m][n][r] + bb, 0.f);
        }
      }
  }
}

// ---------------------------------------------------------------------------
// Kernel 6: gemm2+pair-dot, occupancy-fixed. 32 rows/block -> grid 512
// (2 blocks/CU; R8: 128 blocks = half the chip idle, occ 5.8%).
// Wave w -> cols w*32..w*32+31 (2 n-tiles), rows 32 (2 m-tiles), K=512.
// Pair rows (m*16+4q+{0,1}) and ({2,3}) are lane-local in acc.
// ---------------------------------------------------------------------------
__global__ __launch_bounds__(256) void k_gemm2_dot(
    const bf16_t* __restrict__ A, const bf16_t* __restrict__ BT,
    const float* __restrict__ bias, float* __restrict__ out)
{
  __shared__ float red[4][16];
  const int tid = threadIdx.x;
  const int w = tid >> 6;
  const int lane = tid & 63;
  const int fr = lane & 15;
  const int q = lane >> 4;
  const int fk = q * 8;
  const int row0 = blockIdx.x * 32;
  const int col0 = w * 32;
  constexpr int K = D1;

  f32x4 acc[2][2] = {};
#pragma unroll 4
  for (int k0 = 0; k0 < K; k0 += 32) {
    bf16x8 a[2], b[2];
#pragma unroll
    for (int m = 0; m < 2; ++m)
      a[m] = *reinterpret_cast<const bf16x8*>(A + (size_t)(row0 + m * 16 + fr) * K + k0 + fk);
#pragma unroll
    for (int n = 0; n < 2; ++n)
      b[n] = *reinterpret_cast<const bf16x8*>(BT + (size_t)(col0 + n * 16 + fr) * K + k0 + fk);
#pragma unroll
    for (int m = 0; m < 2; ++m)
#pragma unroll
      for (int n = 0; n < 2; ++n)
        acc[m][n] = __builtin_amdgcn_mfma_f32_16x16x32_bf16(a[m], b[n], acc[m][n], 0, 0, 0);
  }

#pragma unroll
  for (int m = 0; m < 2; ++m) {
    float sA = 0.f, sB = 0.f;  // pairs (rows 4q,4q+1) and (4q+2,4q+3) of m-tile
#pragma unroll
    for (int n = 0; n < 2; ++n) {
      const float bb = bias[col0 + n * 16 + fr];
      const float v0 = acc[m][n][0] + bb;
      const float v1 = acc[m][n][1] + bb;
      const float v2 = acc[m][n][2] + bb;
      const float v3 = acc[m][n][3] + bb;
      sA += v0 * v1;
      sB += v2 * v3;
    }
#pragma unroll
    for (int off = 8; off >= 1; off >>= 1) {  // reduce over the 16 col-lanes
      sA += __shfl_xor(sA, off);
      sB += __shfl_xor(sB, off);
    }
    if (fr == 0) {
      red[w][m * 8 + 2 * q] = sA;
      red[w][m * 8 + 2 * q + 1] = sB;
    }
  }
  __syncthreads();
  if (tid < 16)
    out[blockIdx.x * 16 + tid] =
        (red[0][tid] + red[1][tid]) + (red[2][tid] + red[3][tid]);
}

extern "C" void kernel_launch(void* const* d_in, const int* in_sizes, int n_in,
                              void* d_out, int out_size, void* d_ws, size_t ws_size,
                              hipStream_t stream) {
  const float* table = (const float*)d_in[0];
  const int*   pairs = (const int*)d_in[1];
  const float* conc  = (const float*)d_in[2];
  const float* W0    = (const float*)d_in[3];
  const float* b0    = (const float*)d_in[4];
  const float* W1    = (const float*)d_in[5];
  const float* b1    = (const float*)d_in[6];
  const float* W2    = (const float*)d_in[7];
  const float* b2    = (const float*)d_in[8];
  float* out = (float*)d_out;

  // Workspace (16B-aligned, ~72 MB):
  char* ws = (char*)d_ws;
  float*  h0  = (float*)ws;  ws += (size_t)N_DRUGS * D0 * sizeof(float);    // 17.2 MB
  bf16_t* W1T = (bf16_t*)ws; ws += (size_t)D1 * D0 * sizeof(bf16_t);        //  1.0 MB
  bf16_t* W2T = (bf16_t*)ws; ws += (size_t)D2 * D1 * sizeof(bf16_t);        //  0.13 MB
  bf16_t* H   = (bf16_t*)ws; ws += (size_t)NROWS * D0 * sizeof(bf16_t);     // 33.6 MB
  bf16_t* H1  = (bf16_t*)ws; ws += (size_t)NROWS * D1 * sizeof(bf16_t);     // 16.8 MB
  int* g_idx = (int*)ws;     ws += (size_t)N_DRUGS * MAXNNZ * sizeof(int);  //  3.2 MB
  int* g_cnt = (int*)ws;     ws += (size_t)N_DRUGS * sizeof(int);           // 16.8 KB

  k_convert_w<<<(D0 * D1 + D1 * D2) / 256, 256, 0, stream>>>(W1, W2, W1T, W2T);
  k_scan<<<N_DRUGS, 256, 0, stream>>>((const uint32_t*)table, g_cnt, g_idx);
  k_gather<<<N_DRUGS, 256, 0, stream>>>(W0, g_cnt, g_idx, b0, h0);
  k_build_H<<<NROWS, 256, 0, stream>>>(h0, pairs, conc, W0 + (size_t)N_PROT * D0, H);
  k_gemm1<<<dim3(NROWS / 128, D1 / 128), 256, 0, stream>>>(H, W1T, b1, H1);
  k_gemm2_dot<<<NROWS / 32, 256, 0, stream>>>(H1, W2T, b2, out);
}

// Round 10
// 290.187 us; speedup vs baseline: 6.0065x; 1.6239x over previous
//
#include <hip/hip_runtime.h>
#include <hip/hip_bf16.h>
#include <cstdint>

#define N_PROT 19000
#define N_DRUGS 4200
#define BATCH 8192
#define D0 1024
#define D1 512
#define D2 128
#define NROWS (2 * BATCH)  // 16384 MLP rows, interleaved: r = 2*i + s
#define MAXNNZ 192         // Binomial(19000,0.002): mean 38, sd 6.2 — >20 sigma

// DIAGNOSTIC: only scan is REP'd this round (budget arithmetic says ~100us,
// 2x its HBM floor; it will own top-5 and reveal its bottleneck counters).
#define REP_SCAN 6

typedef __bf16 bf16_t;
typedef __bf16 bf16x8 __attribute__((ext_vector_type(8)));
typedef __bf16 bf16x4 __attribute__((ext_vector_type(4)));
typedef float f32x4 __attribute__((ext_vector_type(4)));

// async global->LDS, 16B per lane, wave-uniform LDS base + lane*16 (HW rule)
#define GLOAD_LDS16(gsrc, ldst)                                        \
  __builtin_amdgcn_global_load_lds(                                    \
      (const __attribute__((address_space(1))) void*)(gsrc),           \
      (__attribute__((address_space(3))) void*)(ldst), 16, 0, 0)

// ---------------------------------------------------------------------------
// Kernel 1: small weight conversions (W1->W1T bf16, W2->W2T bf16).
// ---------------------------------------------------------------------------
__global__ __launch_bounds__(256) void k_convert_w(
    const float* __restrict__ W1, const float* __restrict__ W2,
    bf16_t* __restrict__ W1T, bf16_t* __restrict__ W2T)
{
  const int idx = blockIdx.x * 256 + threadIdx.x;
  if (idx < D0 * D1) {                       // idx = n*D0 + k
    const int nn = idx >> 10, k = idx & (D0 - 1);
    W1T[idx] = (bf16_t)W1[(size_t)k * D1 + nn];
  } else {
    const int j = idx - D0 * D1;             // j = n*D1 + k
    if (j < D1 * D2) {
      const int nn = j >> 9, k = j & (D1 - 1);
      W2T[j] = (bf16_t)W2[(size_t)k * D2 + nn];
    }
  }
}

// ---------------------------------------------------------------------------
// Kernel 2: scan table rows -> per-drug nonzero index lists.
// Unroll-8 (8 independent uint4 loads in flight) + REP x6 for attribution.
// ---------------------------------------------------------------------------
__global__ __launch_bounds__(256) void k_scan(
    const uint32_t* __restrict__ table_u, int* __restrict__ g_cnt,
    int* __restrict__ g_idx)
{
  __shared__ int s_idx[MAXNNZ];
  __shared__ int s_cnt;
  const int d = blockIdx.x;
  const uint4* row = reinterpret_cast<const uint4*>(table_u + (size_t)d * N_PROT);
  constexpr int NQ = N_PROT / 4;  // 4750

#define SCAN_BODY(v, qq)                                                        \
  if ((v).x | (v).y | (v).z | (v).w) {                                          \
    if ((v).x) { int k = atomicAdd(&s_cnt, 1); if (k < MAXNNZ) s_idx[k] = 4 * (qq) + 0; } \
    if ((v).y) { int k = atomicAdd(&s_cnt, 1); if (k < MAXNNZ) s_idx[k] = 4 * (qq) + 1; } \
    if ((v).z) { int k = atomicAdd(&s_cnt, 1); if (k < MAXNNZ) s_idx[k] = 4 * (qq) + 2; } \
    if ((v).w) { int k = atomicAdd(&s_cnt, 1); if (k < MAXNNZ) s_idx[k] = 4 * (qq) + 3; } \
  }

  for (int rep = 0; rep < REP_SCAN; ++rep) {
    __syncthreads();                  // prior rep done reading s_idx/s_cnt
    if (threadIdx.x == 0) s_cnt = 0;
    __syncthreads();

    int q = threadIdx.x;
#pragma unroll
    for (int r = 0; r < 2; ++r) {     // q_base 0..4095: 2 rounds of 8-deep MLP
      uint4 v[8];
#pragma unroll
      for (int u = 0; u < 8; ++u) v[u] = row[q + u * 256];
#pragma unroll
      for (int u = 0; u < 8; ++u) { SCAN_BODY(v[u], q + u * 256) }
      q += 2048;
    }
    {                                 // 4096..4607
      uint4 v0 = row[q];
      uint4 v1 = row[q + 256];
      SCAN_BODY(v0, q)
      SCAN_BODY(v1, q + 256)
      q += 512;
    }
    if (q < NQ) {                     // 4608..4749 (threads 0..141)
      uint4 v = row[q];
      SCAN_BODY(v, q)
    }

    __syncthreads();
    const int n = min(s_cnt, MAXNNZ);
    if (threadIdx.x == 0) g_cnt[d] = n;
    for (int t = threadIdx.x; t < n; t += 256) g_idx[(size_t)d * MAXNNZ + t] = s_idx[t];
  }
#undef SCAN_BODY
}

// ---------------------------------------------------------------------------
// Kernel 3: gather (R9 readfirstlane form — SALU row bases, f32 exact).
// ---------------------------------------------------------------------------
__global__ __launch_bounds__(256) void k_gather(
    const float* __restrict__ W0, const int* __restrict__ g_cnt,
    const int* __restrict__ g_idx, const float* __restrict__ b0,
    float* __restrict__ h0)
{
  __shared__ int s_idx[MAXNNZ];
  const int d = blockIdx.x;
  const int n = g_cnt[d];
  for (int t = threadIdx.x; t < n; t += 256) s_idx[t] = g_idx[(size_t)d * MAXNNZ + t];
  __syncthreads();

  const int j4 = threadIdx.x * 4;
  f32x4 a0 = {0.f, 0.f, 0.f, 0.f}, a1 = a0, a2 = a0, a3 = a0;
  int t = 0;
  for (; t + 4 <= n; t += 4) {
    const float* p0 = W0 + (size_t)__builtin_amdgcn_readfirstlane(s_idx[t + 0]) * D0;
    const float* p1 = W0 + (size_t)__builtin_amdgcn_readfirstlane(s_idx[t + 1]) * D0;
    const float* p2 = W0 + (size_t)__builtin_amdgcn_readfirstlane(s_idx[t + 2]) * D0;
    const float* p3 = W0 + (size_t)__builtin_amdgcn_readfirstlane(s_idx[t + 3]) * D0;
    a0 += *reinterpret_cast<const f32x4*>(p0 + j4);
    a1 += *reinterpret_cast<const f32x4*>(p1 + j4);
    a2 += *reinterpret_cast<const f32x4*>(p2 + j4);
    a3 += *reinterpret_cast<const f32x4*>(p3 + j4);
  }
  for (; t < n; ++t) {
    const float* p = W0 + (size_t)__builtin_amdgcn_readfirstlane(s_idx[t]) * D0;
    a0 += *reinterpret_cast<const f32x4*>(p + j4);
  }
  f32x4 bb = *reinterpret_cast<const f32x4*>(b0 + j4);
  f32x4 r = ((a0 + a1) + (a2 + a3)) + bb;
  *reinterpret_cast<f32x4*>(h0 + (size_t)d * D0 + j4) = r;
}

// ---------------------------------------------------------------------------
// Kernel 4: H[r][:] = relu(h0[drug(r)] + c(r)*W0_last), bf16 (b0 in h0).
// ---------------------------------------------------------------------------
__global__ __launch_bounds__(256) void k_build_H(
    const float* __restrict__ h0, const int* __restrict__ pairs,
    const float* __restrict__ conc, const float* __restrict__ W0last,
    bf16_t* __restrict__ H)
{
  const int r = blockIdx.x;
  const int drug = pairs[r];
  const float c = conc[3 * (r >> 1) + 1 + (r & 1)];

  const int j = threadIdx.x * 4;
  float4 hv = *reinterpret_cast<const float4*>(h0 + (size_t)drug * D0 + j);
  float4 wl = *reinterpret_cast<const float4*>(W0last + j);
  bf16x4 o;
  o[0] = (bf16_t)fmaxf(hv.x + c * wl.x, 0.f);
  o[1] = (bf16_t)fmaxf(hv.y + c * wl.y, 0.f);
  o[2] = (bf16_t)fmaxf(hv.z + c * wl.z, 0.f);
  o[3] = (bf16_t)fmaxf(hv.w + c * wl.w, 0.f);
  *reinterpret_cast<bf16x4*>(H + (size_t)r * D0 + j) = o;
}

// ---------------------------------------------------------------------------
// Kernel 5: m97-style GEMM1 + GRANULE SWIZZLE (bank-conflict fix).
// R9 counters: SQ_LDS_BANK_CONFLICT 2.1M/rep — 64B LDS rows => fr and fr+2
// share a bank base => 8-way conflict on ds_read_b128 (m136: 2.94x).
// Fix per rule #21 (both-sides-or-neither with global_load_lds):
//   LDS dest stays linear; global SOURCE pre-swizzled:
//     lane fetches granule (lane&3) ^ ((lane>>3)&3)   [= qL ^ swz(row)]
//   read side swizzled:  granule q ^ ((fr>>1)&3)      [= swz(row), row=..+fr]
// For fixed q, 16 lanes now map to 8 bank-quads x exactly 2 = 2-way = free.
// ---------------------------------------------------------------------------
__global__ __launch_bounds__(256) void k_gemm1(
    const bf16_t* __restrict__ A, const bf16_t* __restrict__ BT,
    const float* __restrict__ bias, bf16_t* __restrict__ C)
{
  constexpr int K = D0;       // 1024
  constexpr int N = D1;       // 512
  constexpr int NT = K / 32;  // 32 K-steps
  __shared__ bf16_t sA[2][128 * 32];
  __shared__ bf16_t sB[2][128 * 32];

  const int tid = threadIdx.x;
  const int w = tid >> 6;
  const int lane = tid & 63;
  const int wr = w >> 1, wc = w & 1;
  const int row0 = blockIdx.x * 128;
  const int col0 = blockIdx.y * 128;
  const int fr = lane & 15;
  const int q = lane >> 4;

  // staging: per-lane global source carries the INVERSE swizzle
  const int srow0 = (w * 2 + 0) * 16 + (lane >> 2);
  const int srow1 = (w * 2 + 1) * 16 + (lane >> 2);
  const int skel = (((lane & 3) ^ ((lane >> 3) & 3))) * 8;  // swizzled granule
  const bf16_t* a_src0 = A + (size_t)(row0 + srow0) * K + skel;
  const bf16_t* a_src1 = A + (size_t)(row0 + srow1) * K + skel;
  const bf16_t* b_src0 = BT + (size_t)(col0 + srow0) * K + skel;
  const bf16_t* b_src1 = BT + (size_t)(col0 + srow1) * K + skel;
  const int ldst0 = (w * 2 + 0) * 512;
  const int ldst1 = (w * 2 + 1) * 512;

  auto stage = [&](int buf, int k0) {
    GLOAD_LDS16(a_src0 + k0, &sA[buf][ldst0]);
    GLOAD_LDS16(a_src1 + k0, &sA[buf][ldst1]);
    GLOAD_LDS16(b_src0 + k0, &sB[buf][ldst0]);
    GLOAD_LDS16(b_src1 + k0, &sB[buf][ldst1]);
  };

  // read-side swizzled granule (row = ...16*m + fr, swz = (row>>1)&3 = (fr>>1)&3)
  const int qs = (q ^ ((fr >> 1) & 3)) * 8;

  f32x4 acc[4][4] = {};
  stage(0, 0);
  for (int ks = 0; ks < NT; ++ks) {
    const int buf = ks & 1;
    __syncthreads();
    if (ks + 1 < NT) stage(buf ^ 1, (ks + 1) * 32);

    bf16x8 a[4], b[4];
#pragma unroll
    for (int m = 0; m < 4; ++m)
      a[m] = *reinterpret_cast<const bf16x8*>(&sA[buf][(wr * 64 + m * 16 + fr) * 32 + qs]);
#pragma unroll
    for (int n = 0; n < 4; ++n)
      b[n] = *reinterpret_cast<const bf16x8*>(&sB[buf][(wc * 64 + n * 16 + fr) * 32 + qs]);
#pragma unroll
    for (int m = 0; m < 4; ++m)
#pragma unroll
      for (int n = 0; n < 4; ++n)
        acc[m][n] = __builtin_amdgcn_mfma_f32_16x16x32_bf16(a[m], b[n], acc[m][n], 0, 0, 0);
  }

#pragma unroll
  for (int m = 0; m < 4; ++m)
#pragma unroll
    for (int n = 0; n < 4; ++n) {
      const int col = col0 + wc * 64 + n * 16 + fr;
      const float bb = bias[col];
#pragma unroll
      for (int r = 0; r < 4; ++r) {
        const int row = row0 + wr * 64 + m * 16 + 4 * q + r;
        C[(size_t)row * N + col] = (bf16_t)fmaxf(acc[m][n][r] + bb, 0.f);
      }
    }
}

// ---------------------------------------------------------------------------
// Kernel 6: gemm2+pair-dot (R9 form: 32 rows/block, grid 512 = 2/CU).
// ---------------------------------------------------------------------------
__global__ __launch_bounds__(256) void k_gemm2_dot(
    const bf16_t* __restrict__ A, const bf16_t* __restrict__ BT,
    const float* __restrict__ bias, float* __restrict__ out)
{
  __shared__ float red[4][16];
  const int tid = threadIdx.x;
  const int w = tid >> 6;
  const int lane = tid & 63;
  const int fr = lane & 15;
  const int q = lane >> 4;
  const int fk = q * 8;
  const int row0 = blockIdx.x * 32;
  const int col0 = w * 32;
  constexpr int K = D1;

  f32x4 acc[2][2] = {};
#pragma unroll 4
  for (int k0 = 0; k0 < K; k0 += 32) {
    bf16x8 a[2], b[2];
#pragma unroll
    for (int m = 0; m < 2; ++m)
      a[m] = *reinterpret_cast<const bf16x8*>(A + (size_t)(row0 + m * 16 + fr) * K + k0 + fk);
#pragma unroll
    for (int n = 0; n < 2; ++n)
      b[n] = *reinterpret_cast<const bf16x8*>(BT + (size_t)(col0 + n * 16 + fr) * K + k0 + fk);
#pragma unroll
    for (int m = 0; m < 2; ++m)
#pragma unroll
      for (int n = 0; n < 2; ++n)
        acc[m][n] = __builtin_amdgcn_mfma_f32_16x16x32_bf16(a[m], b[n], acc[m][n], 0, 0, 0);
  }

#pragma unroll
  for (int m = 0; m < 2; ++m) {
    float sA = 0.f, sB = 0.f;
#pragma unroll
    for (int n = 0; n < 2; ++n) {
      const float bb = bias[col0 + n * 16 + fr];
      const float v0 = acc[m][n][0] + bb;
      const float v1 = acc[m][n][1] + bb;
      const float v2 = acc[m][n][2] + bb;
      const float v3 = acc[m][n][3] + bb;
      sA += v0 * v1;
      sB += v2 * v3;
    }
#pragma unroll
    for (int off = 8; off >= 1; off >>= 1) {
      sA += __shfl_xor(sA, off);
      sB += __shfl_xor(sB, off);
    }
    if (fr == 0) {
      red[w][m * 8 + 2 * q] = sA;
      red[w][m * 8 + 2 * q + 1] = sB;
    }
  }
  __syncthreads();
  if (tid < 16)
    out[blockIdx.x * 16 + tid] =
        (red[0][tid] + red[1][tid]) + (red[2][tid] + red[3][tid]);
}

extern "C" void kernel_launch(void* const* d_in, const int* in_sizes, int n_in,
                              void* d_out, int out_size, void* d_ws, size_t ws_size,
                              hipStream_t stream) {
  const float* table = (const float*)d_in[0];
  const int*   pairs = (const int*)d_in[1];
  const float* conc  = (const float*)d_in[2];
  const float* W0    = (const float*)d_in[3];
  const float* b0    = (const float*)d_in[4];
  const float* W1    = (const float*)d_in[5];
  const float* b1    = (const float*)d_in[6];
  const float* W2    = (const float*)d_in[7];
  const float* b2    = (const float*)d_in[8];
  float* out = (float*)d_out;

  // Workspace (16B-aligned, ~72 MB):
  char* ws = (char*)d_ws;
  float*  h0  = (float*)ws;  ws += (size_t)N_DRUGS * D0 * sizeof(float);    // 17.2 MB
  bf16_t* W1T = (bf16_t*)ws; ws += (size_t)D1 * D0 * sizeof(bf16_t);        //  1.0 MB
  bf16_t* W2T = (bf16_t*)ws; ws += (size_t)D2 * D1 * sizeof(bf16_t);        //  0.13 MB
  bf16_t* H   = (bf16_t*)ws; ws += (size_t)NROWS * D0 * sizeof(bf16_t);     // 33.6 MB
  bf16_t* H1  = (bf16_t*)ws; ws += (size_t)NROWS * D1 * sizeof(bf16_t);     // 16.8 MB
  int* g_idx = (int*)ws;     ws += (size_t)N_DRUGS * MAXNNZ * sizeof(int);  //  3.2 MB
  int* g_cnt = (int*)ws;     ws += (size_t)N_DRUGS * sizeof(int);           // 16.8 KB

  k_convert_w<<<(D0 * D1 + D1 * D2) / 256, 256, 0, stream>>>(W1, W2, W1T, W2T);
  k_scan<<<N_DRUGS, 256, 0, stream>>>((const uint32_t*)table, g_cnt, g_idx);
  k_gather<<<N_DRUGS, 256, 0, stream>>>(W0, g_cnt, g_idx, b0, h0);
  k_build_H<<<NROWS, 256, 0, stream>>>(h0, pairs, conc, W0 + (size_t)N_PROT * D0, H);
  k_gemm1<<<dim3(NROWS / 128, D1 / 128), 256, 0, stream>>>(H, W1T, b1, H1);
  k_gemm2_dot<<<NROWS / 32, 256, 0, stream>>>(H1, W2T, b2, out);
}

// Round 11
// 230.258 us; speedup vs baseline: 7.5699x; 1.2603x over previous
//
#include <hip/hip_runtime.h>
#include <hip/hip_bf16.h>
#include <cstdint>

#define N_PROT 19000
#define N_DRUGS 4200
#define BATCH 8192
#define D0 1024
#define D1 512
#define D2 128
#define NROWS (2 * BATCH)  // 16384 MLP rows, interleaved: r = 2*i + s
#define MAXNNZ 192         // Binomial(19000,0.002): mean 38, sd 6.2 — >20 sigma

typedef __bf16 bf16_t;
typedef __bf16 bf16x8 __attribute__((ext_vector_type(8)));
typedef __bf16 bf16x4 __attribute__((ext_vector_type(4)));
typedef float f32x4 __attribute__((ext_vector_type(4)));

// async global->LDS, 16B per lane, wave-uniform LDS base + lane*16 (HW rule)
#define GLOAD_LDS16(gsrc, ldst)                                        \
  __builtin_amdgcn_global_load_lds(                                    \
      (const __attribute__((address_space(1))) void*)(gsrc),           \
      (__attribute__((address_space(3))) void*)(ldst), 16, 0, 0)

// ---------------------------------------------------------------------------
// Kernel 1: small weight conversions (W1->W1T bf16, W2->W2T bf16).
// ---------------------------------------------------------------------------
__global__ __launch_bounds__(256) void k_convert_w(
    const float* __restrict__ W1, const float* __restrict__ W2,
    bf16_t* __restrict__ W1T, bf16_t* __restrict__ W2T)
{
  const int idx = blockIdx.x * 256 + threadIdx.x;
  if (idx < D0 * D1) {                       // idx = n*D0 + k
    const int nn = idx >> 10, k = idx & (D0 - 1);
    W1T[idx] = (bf16_t)W1[(size_t)k * D1 + nn];
  } else {
    const int j = idx - D0 * D1;             // j = n*D1 + k
    if (j < D1 * D2) {
      const int nn = j >> 9, k = j & (D1 - 1);
      W2T[j] = (bf16_t)W2[(size_t)k * D2 + nn];
    }
  }
}

// ---------------------------------------------------------------------------
// Kernel 2: scan table rows -> per-drug nonzero index lists. Unroll-8.
// Measured (R10 REP x6): ~30us = mixed L3/HBM floor for the 319MB table read.
// ---------------------------------------------------------------------------
__global__ __launch_bounds__(256) void k_scan(
    const uint32_t* __restrict__ table_u, int* __restrict__ g_cnt,
    int* __restrict__ g_idx)
{
  __shared__ int s_idx[MAXNNZ];
  __shared__ int s_cnt;
  const int d = blockIdx.x;
  if (threadIdx.x == 0) s_cnt = 0;
  __syncthreads();
  const uint4* row = reinterpret_cast<const uint4*>(table_u + (size_t)d * N_PROT);
  constexpr int NQ = N_PROT / 4;  // 4750

#define SCAN_BODY(v, qq)                                                        \
  if ((v).x | (v).y | (v).z | (v).w) {                                          \
    if ((v).x) { int k = atomicAdd(&s_cnt, 1); if (k < MAXNNZ) s_idx[k] = 4 * (qq) + 0; } \
    if ((v).y) { int k = atomicAdd(&s_cnt, 1); if (k < MAXNNZ) s_idx[k] = 4 * (qq) + 1; } \
    if ((v).z) { int k = atomicAdd(&s_cnt, 1); if (k < MAXNNZ) s_idx[k] = 4 * (qq) + 2; } \
    if ((v).w) { int k = atomicAdd(&s_cnt, 1); if (k < MAXNNZ) s_idx[k] = 4 * (qq) + 3; } \
  }

  int q = threadIdx.x;
#pragma unroll
  for (int r = 0; r < 2; ++r) {     // q_base 0..4095: 8 independent loads deep
    uint4 v[8];
#pragma unroll
    for (int u = 0; u < 8; ++u) v[u] = row[q + u * 256];
#pragma unroll
    for (int u = 0; u < 8; ++u) { SCAN_BODY(v[u], q + u * 256) }
    q += 2048;
  }
  {                                 // 4096..4607
    uint4 v0 = row[q];
    uint4 v1 = row[q + 256];
    SCAN_BODY(v0, q)
    SCAN_BODY(v1, q + 256)
    q += 512;
  }
  if (q < NQ) {                     // 4608..4749 (threads 0..141)
    uint4 v = row[q];
    SCAN_BODY(v, q)
  }
#undef SCAN_BODY

  __syncthreads();
  const int n = min(s_cnt, MAXNNZ);
  if (threadIdx.x == 0) g_cnt[d] = n;
  for (int t = threadIdx.x; t < n; t += 256) g_idx[(size_t)d * MAXNNZ + t] = s_idx[t];
}

// ---------------------------------------------------------------------------
// Kernel 3: gather (readfirstlane SALU row bases; f32 exact; ~8us measured-ish).
// ---------------------------------------------------------------------------
__global__ __launch_bounds__(256) void k_gather(
    const float* __restrict__ W0, const int* __restrict__ g_cnt,
    const int* __restrict__ g_idx, const float* __restrict__ b0,
    float* __restrict__ h0)
{
  __shared__ int s_idx[MAXNNZ];
  const int d = blockIdx.x;
  const int n = g_cnt[d];
  for (int t = threadIdx.x; t < n; t += 256) s_idx[t] = g_idx[(size_t)d * MAXNNZ + t];
  __syncthreads();

  const int j4 = threadIdx.x * 4;
  f32x4 a0 = {0.f, 0.f, 0.f, 0.f}, a1 = a0, a2 = a0, a3 = a0;
  int t = 0;
  for (; t + 4 <= n; t += 4) {
    const float* p0 = W0 + (size_t)__builtin_amdgcn_readfirstlane(s_idx[t + 0]) * D0;
    const float* p1 = W0 + (size_t)__builtin_amdgcn_readfirstlane(s_idx[t + 1]) * D0;
    const float* p2 = W0 + (size_t)__builtin_amdgcn_readfirstlane(s_idx[t + 2]) * D0;
    const float* p3 = W0 + (size_t)__builtin_amdgcn_readfirstlane(s_idx[t + 3]) * D0;
    a0 += *reinterpret_cast<const f32x4*>(p0 + j4);
    a1 += *reinterpret_cast<const f32x4*>(p1 + j4);
    a2 += *reinterpret_cast<const f32x4*>(p2 + j4);
    a3 += *reinterpret_cast<const f32x4*>(p3 + j4);
  }
  for (; t < n; ++t) {
    const float* p = W0 + (size_t)__builtin_amdgcn_readfirstlane(s_idx[t]) * D0;
    a0 += *reinterpret_cast<const f32x4*>(p + j4);
  }
  f32x4 bb = *reinterpret_cast<const f32x4*>(b0 + j4);
  f32x4 r = ((a0 + a1) + (a2 + a3)) + bb;
  *reinterpret_cast<f32x4*>(h0 + (size_t)d * D0 + j4) = r;
}

// ---------------------------------------------------------------------------
// Kernel 4: H[r][:] = relu(h0[drug(r)] + c(r)*W0_last), bf16 (b0 in h0).
// ---------------------------------------------------------------------------
__global__ __launch_bounds__(256) void k_build_H(
    const float* __restrict__ h0, const int* __restrict__ pairs,
    const float* __restrict__ conc, const float* __restrict__ W0last,
    bf16_t* __restrict__ H)
{
  const int r = blockIdx.x;
  const int drug = pairs[r];
  const float c = conc[3 * (r >> 1) + 1 + (r & 1)];

  const int j = threadIdx.x * 4;
  float4 hv = *reinterpret_cast<const float4*>(h0 + (size_t)drug * D0 + j);
  float4 wl = *reinterpret_cast<const float4*>(W0last + j);
  bf16x4 o;
  o[0] = (bf16_t)fmaxf(hv.x + c * wl.x, 0.f);
  o[1] = (bf16_t)fmaxf(hv.y + c * wl.y, 0.f);
  o[2] = (bf16_t)fmaxf(hv.z + c * wl.z, 0.f);
  o[3] = (bf16_t)fmaxf(hv.w + c * wl.w, 0.f);
  *reinterpret_cast<bf16x4*>(H + (size_t)r * D0 + j) = o;
}

// ---------------------------------------------------------------------------
// Kernel 5: m97-style GEMM1 with granule swizzle (R10 form; conflicts fixed:
// R9 had 2.1M SQ_LDS_BANK_CONFLICT/rep from 64B LDS rows; source-preswizzle
// + swizzled read per rule #21).
// ---------------------------------------------------------------------------
__global__ __launch_bounds__(256) void k_gemm1(
    const bf16_t* __restrict__ A, const bf16_t* __restrict__ BT,
    const float* __restrict__ bias, bf16_t* __restrict__ C)
{
  constexpr int K = D0;       // 1024
  constexpr int N = D1;       // 512
  constexpr int NT = K / 32;  // 32 K-steps
  __shared__ bf16_t sA[2][128 * 32];
  __shared__ bf16_t sB[2][128 * 32];

  const int tid = threadIdx.x;
  const int w = tid >> 6;
  const int lane = tid & 63;
  const int wr = w >> 1, wc = w & 1;
  const int row0 = blockIdx.x * 128;
  const int col0 = blockIdx.y * 128;
  const int fr = lane & 15;
  const int q = lane >> 4;

  const int srow0 = (w * 2 + 0) * 16 + (lane >> 2);
  const int srow1 = (w * 2 + 1) * 16 + (lane >> 2);
  const int skel = (((lane & 3) ^ ((lane >> 3) & 3))) * 8;  // inverse swizzle
  const bf16_t* a_src0 = A + (size_t)(row0 + srow0) * K + skel;
  const bf16_t* a_src1 = A + (size_t)(row0 + srow1) * K + skel;
  const bf16_t* b_src0 = BT + (size_t)(col0 + srow0) * K + skel;
  const bf16_t* b_src1 = BT + (size_t)(col0 + srow1) * K + skel;
  const int ldst0 = (w * 2 + 0) * 512;
  const int ldst1 = (w * 2 + 1) * 512;

  auto stage = [&](int buf, int k0) {
    GLOAD_LDS16(a_src0 + k0, &sA[buf][ldst0]);
    GLOAD_LDS16(a_src1 + k0, &sA[buf][ldst1]);
    GLOAD_LDS16(b_src0 + k0, &sB[buf][ldst0]);
    GLOAD_LDS16(b_src1 + k0, &sB[buf][ldst1]);
  };

  const int qs = (q ^ ((fr >> 1) & 3)) * 8;  // read-side swizzled granule

  f32x4 acc[4][4] = {};
  stage(0, 0);
  for (int ks = 0; ks < NT; ++ks) {
    const int buf = ks & 1;
    __syncthreads();
    if (ks + 1 < NT) stage(buf ^ 1, (ks + 1) * 32);

    bf16x8 a[4], b[4];
#pragma unroll
    for (int m = 0; m < 4; ++m)
      a[m] = *reinterpret_cast<const bf16x8*>(&sA[buf][(wr * 64 + m * 16 + fr) * 32 + qs]);
#pragma unroll
    for (int n = 0; n < 4; ++n)
      b[n] = *reinterpret_cast<const bf16x8*>(&sB[buf][(wc * 64 + n * 16 + fr) * 32 + qs]);
#pragma unroll
    for (int m = 0; m < 4; ++m)
#pragma unroll
      for (int n = 0; n < 4; ++n)
        acc[m][n] = __builtin_amdgcn_mfma_f32_16x16x32_bf16(a[m], b[n], acc[m][n], 0, 0, 0);
  }

#pragma unroll
  for (int m = 0; m < 4; ++m)
#pragma unroll
    for (int n = 0; n < 4; ++n) {
      const int col = col0 + wc * 64 + n * 16 + fr;
      const float bb = bias[col];
#pragma unroll
      for (int r = 0; r < 4; ++r) {
        const int row = row0 + wr * 64 + m * 16 + 4 * q + r;
        C[(size_t)row * N + col] = (bf16_t)fmaxf(acc[m][n][r] + bb, 0.f);
      }
    }
}

// ---------------------------------------------------------------------------
// Kernel 6: gemm2+pair-dot (32 rows/block, grid 512 = 2/CU).
// ---------------------------------------------------------------------------
__global__ __launch_bounds__(256) void k_gemm2_dot(
    const bf16_t* __restrict__ A, const bf16_t* __restrict__ BT,
    const float* __restrict__ bias, float* __restrict__ out)
{
  __shared__ float red[4][16];
  const int tid = threadIdx.x;
  const int w = tid >> 6;
  const int lane = tid & 63;
  const int fr = lane & 15;
  const int q = lane >> 4;
  const int fk = q * 8;
  const int row0 = blockIdx.x * 32;
  const int col0 = w * 32;
  constexpr int K = D1;

  f32x4 acc[2][2] = {};
#pragma unroll 4
  for (int k0 = 0; k0 < K; k0 += 32) {
    bf16x8 a[2], b[2];
#pragma unroll
    for (int m = 0; m < 2; ++m)
      a[m] = *reinterpret_cast<const bf16x8*>(A + (size_t)(row0 + m * 16 + fr) * K + k0 + fk);
#pragma unroll
    for (int n = 0; n < 2; ++n)
      b[n] = *reinterpret_cast<const bf16x8*>(BT + (size_t)(col0 + n * 16 + fr) * K + k0 + fk);
#pragma unroll
    for (int m = 0; m < 2; ++m)
#pragma unroll
      for (int n = 0; n < 2; ++n)
        acc[m][n] = __builtin_amdgcn_mfma_f32_16x16x32_bf16(a[m], b[n], acc[m][n], 0, 0, 0);
  }

#pragma unroll
  for (int m = 0; m < 2; ++m) {
    float sA = 0.f, sB = 0.f;
#pragma unroll
    for (int n = 0; n < 2; ++n) {
      const float bb = bias[col0 + n * 16 + fr];
      const float v0 = acc[m][n][0] + bb;
      const float v1 = acc[m][n][1] + bb;
      const float v2 = acc[m][n][2] + bb;
      const float v3 = acc[m][n][3] + bb;
      sA += v0 * v1;
      sB += v2 * v3;
    }
#pragma unroll
    for (int off = 8; off >= 1; off >>= 1) {
      sA += __shfl_xor(sA, off);
      sB += __shfl_xor(sB, off);
    }
    if (fr == 0) {
      red[w][m * 8 + 2 * q] = sA;
      red[w][m * 8 + 2 * q + 1] = sB;
    }
  }
  __syncthreads();
  if (tid < 16)
    out[blockIdx.x * 16 + tid] =
        (red[0][tid] + red[1][tid]) + (red[2][tid] + red[3][tid]);
}

extern "C" void kernel_launch(void* const* d_in, const int* in_sizes, int n_in,
                              void* d_out, int out_size, void* d_ws, size_t ws_size,
                              hipStream_t stream) {
  const float* table = (const float*)d_in[0];
  const int*   pairs = (const int*)d_in[1];
  const float* conc  = (const float*)d_in[2];
  const float* W0    = (const float*)d_in[3];
  const float* b0    = (const float*)d_in[4];
  const float* W1    = (const float*)d_in[5];
  const float* b1    = (const float*)d_in[6];
  const float* W2    = (const float*)d_in[7];
  const float* b2    = (const float*)d_in[8];
  float* out = (float*)d_out;

  // Workspace (16B-aligned, ~72 MB):
  char* ws = (char*)d_ws;
  float*  h0  = (float*)ws;  ws += (size_t)N_DRUGS * D0 * sizeof(float);    // 17.2 MB
  bf16_t* W1T = (bf16_t*)ws; ws += (size_t)D1 * D0 * sizeof(bf16_t);        //  1.0 MB
  bf16_t* W2T = (bf16_t*)ws; ws += (size_t)D2 * D1 * sizeof(bf16_t);        //  0.13 MB
  bf16_t* H   = (bf16_t*)ws; ws += (size_t)NROWS * D0 * sizeof(bf16_t);     // 33.6 MB
  bf16_t* H1  = (bf16_t*)ws; ws += (size_t)NROWS * D1 * sizeof(bf16_t);     // 16.8 MB
  int* g_idx = (int*)ws;     ws += (size_t)N_DRUGS * MAXNNZ * sizeof(int);  //  3.2 MB
  int* g_cnt = (int*)ws;     ws += (size_t)N_DRUGS * sizeof(int);           // 16.8 KB

  k_convert_w<<<(D0 * D1 + D1 * D2) / 256, 256, 0, stream>>>(W1, W2, W1T, W2T);
  k_scan<<<N_DRUGS, 256, 0, stream>>>((const uint32_t*)table, g_cnt, g_idx);
  k_gather<<<N_DRUGS, 256, 0, stream>>>(W0, g_cnt, g_idx, b0, h0);
  k_build_H<<<NROWS, 256, 0, stream>>>(h0, pairs, conc, W0 + (size_t)N_PROT * D0, H);
  k_gemm1<<<dim3(NROWS / 128, D1 / 128), 256, 0, stream>>>(H, W1T, b1, H1);
  k_gemm2_dot<<<NROWS / 32, 256, 0, stream>>>(H1, W2T, b2, out);
}

// Round 12
// 171.176 us; speedup vs baseline: 10.1826x; 1.3452x over previous
//
#include <hip/hip_runtime.h>
#include <hip/hip_bf16.h>
#include <cstdint>

#define N_PROT 19000
#define N_DRUGS 4200
#define BATCH 8192
#define D0 1024
#define D1 512
#define D2 128
#define NROWS (2 * BATCH)  // 16384 MLP rows, interleaved: r = 2*i + s
#define MAXNNZ 192         // Binomial(19000,0.002): mean 38, sd 6.2 — >20 sigma
#define BR 64              // rows per fused block -> grid 256 = 1/CU
#define NCHUNK 8           // gather column chunks (one per XCD)
#define CCOLS (D0 / NCHUNK)

typedef __bf16 bf16_t;
typedef __bf16 bf16x8 __attribute__((ext_vector_type(8)));
typedef __bf16 bf16x4 __attribute__((ext_vector_type(4)));
typedef __bf16 bf16x2 __attribute__((ext_vector_type(2)));
typedef float f32x4 __attribute__((ext_vector_type(4)));
typedef float f32x8 __attribute__((ext_vector_type(8)));

// ---------------------------------------------------------------------------
// Kernel 1: weight conversions. W0->W0b bf16 (39MB, L2/L3-resident for the
// chunked gather); W1->W1T bf16; W2->W2T bf16.
// ---------------------------------------------------------------------------
__global__ __launch_bounds__(256) void k_convert(
    const float* __restrict__ W0, const float* __restrict__ W1,
    const float* __restrict__ W2, bf16_t* __restrict__ W0b,
    bf16_t* __restrict__ W1T, bf16_t* __restrict__ W2T)
{
  const int S = gridDim.x * 256;
  const int tid0 = blockIdx.x * 256 + threadIdx.x;
  constexpr int NV0 = N_PROT * D0 / 4;  // 4,864,000 float4 groups

  int v = tid0;
  for (; v + 3 * S < NV0; v += 4 * S) {
    f32x4 w0 = reinterpret_cast<const f32x4*>(W0)[v];
    f32x4 w1 = reinterpret_cast<const f32x4*>(W0)[v + S];
    f32x4 w2 = reinterpret_cast<const f32x4*>(W0)[v + 2 * S];
    f32x4 w3 = reinterpret_cast<const f32x4*>(W0)[v + 3 * S];
    bf16x4 o0 = {(bf16_t)w0[0], (bf16_t)w0[1], (bf16_t)w0[2], (bf16_t)w0[3]};
    bf16x4 o1 = {(bf16_t)w1[0], (bf16_t)w1[1], (bf16_t)w1[2], (bf16_t)w1[3]};
    bf16x4 o2 = {(bf16_t)w2[0], (bf16_t)w2[1], (bf16_t)w2[2], (bf16_t)w2[3]};
    bf16x4 o3 = {(bf16_t)w3[0], (bf16_t)w3[1], (bf16_t)w3[2], (bf16_t)w3[3]};
    reinterpret_cast<bf16x4*>(W0b)[v] = o0;
    reinterpret_cast<bf16x4*>(W0b)[v + S] = o1;
    reinterpret_cast<bf16x4*>(W0b)[v + 2 * S] = o2;
    reinterpret_cast<bf16x4*>(W0b)[v + 3 * S] = o3;
  }
  for (; v < NV0; v += S) {
    f32x4 w = reinterpret_cast<const f32x4*>(W0)[v];
    bf16x4 o = {(bf16_t)w[0], (bf16_t)w[1], (bf16_t)w[2], (bf16_t)w[3]};
    reinterpret_cast<bf16x4*>(W0b)[v] = o;
  }
  for (int idx = tid0; idx < D0 * D1; idx += S) {   // idx = n*D0 + k
    const int n = idx >> 10, k = idx & (D0 - 1);
    W1T[idx] = (bf16_t)W1[(size_t)k * D1 + n];
  }
  for (int idx = tid0; idx < D1 * D2; idx += S) {   // idx = n*D1 + k
    const int n = idx >> 9, k = idx & (D1 - 1);
    W2T[idx] = (bf16_t)W2[(size_t)k * D2 + n];
  }
}

// ---------------------------------------------------------------------------
// Kernel 2: scan table rows -> per-drug nonzero index lists (R4's unroll-2
// form — the version in the 157.4us best run).
// ---------------------------------------------------------------------------
__global__ __launch_bounds__(256) void k_scan(
    const uint32_t* __restrict__ table_u, int* __restrict__ g_cnt,
    int* __restrict__ g_idx)
{
  __shared__ int s_idx[MAXNNZ];
  __shared__ int s_cnt;
  const int d = blockIdx.x;
  if (threadIdx.x == 0) s_cnt = 0;
  __syncthreads();

  const uint4* row = reinterpret_cast<const uint4*>(table_u + (size_t)d * N_PROT);
  constexpr int NQ = N_PROT / 4;  // 4750

#define SCAN_BODY(v, qq)                                                        \
  if ((v).x | (v).y | (v).z | (v).w) {                                          \
    if ((v).x) { int k = atomicAdd(&s_cnt, 1); if (k < MAXNNZ) s_idx[k] = 4 * (qq) + 0; } \
    if ((v).y) { int k = atomicAdd(&s_cnt, 1); if (k < MAXNNZ) s_idx[k] = 4 * (qq) + 1; } \
    if ((v).z) { int k = atomicAdd(&s_cnt, 1); if (k < MAXNNZ) s_idx[k] = 4 * (qq) + 2; } \
    if ((v).w) { int k = atomicAdd(&s_cnt, 1); if (k < MAXNNZ) s_idx[k] = 4 * (qq) + 3; } \
  }

  int q = threadIdx.x;
  for (; q + 256 < NQ; q += 512) {
    uint4 v0 = row[q];
    uint4 v1 = row[q + 256];
    SCAN_BODY(v0, q)
    SCAN_BODY(v1, q + 256)
  }
  for (; q < NQ; q += 256) {
    uint4 v = row[q];
    SCAN_BODY(v, q)
  }
#undef SCAN_BODY

  __syncthreads();
  const int n = min(s_cnt, MAXNNZ);
  if (threadIdx.x == 0) g_cnt[d] = n;
  for (int t = threadIdx.x; t < n; t += 256) g_idx[(size_t)d * MAXNNZ + t] = s_idx[t];
}

// ---------------------------------------------------------------------------
// Kernel 3: XCD-chunked gather (R4/R8 structure, 17.6us measured VALU-bound)
// + readfirstlane-scalarized row bases (SALU addressing: the valid half of
// R9's fix, WITHOUT giving up L2-chunking/bf16 like R9 mistakenly did).
// h0[d][:] = sum of listed W0b rows + b0. chunk = blockIdx%8 == XCD.
// ---------------------------------------------------------------------------
__global__ __launch_bounds__(64) void k_gather(
    const bf16_t* __restrict__ W0b, const int* __restrict__ g_cnt,
    const int* __restrict__ g_idx, const float* __restrict__ b0,
    float* __restrict__ h0)
{
  __shared__ int s_idx[MAXNNZ];
  const int chunk = blockIdx.x & (NCHUNK - 1);
  const int d = blockIdx.x >> 3;
  const int n = g_cnt[d];
  for (int t = threadIdx.x; t < n; t += 64) s_idx[t] = g_idx[(size_t)d * MAXNNZ + t];
  __syncthreads();

  const int col = chunk * CCOLS + threadIdx.x * 2;
  float c0 = 0.f, c1 = 0.f, d0_ = 0.f, d1_ = 0.f;
  float e0 = 0.f, e1 = 0.f, f0 = 0.f, f1 = 0.f;
  int t = 0;
  for (; t + 4 <= n; t += 4) {
    const bf16_t* p0 = W0b + (size_t)__builtin_amdgcn_readfirstlane(s_idx[t + 0]) * D0;
    const bf16_t* p1 = W0b + (size_t)__builtin_amdgcn_readfirstlane(s_idx[t + 1]) * D0;
    const bf16_t* p2 = W0b + (size_t)__builtin_amdgcn_readfirstlane(s_idx[t + 2]) * D0;
    const bf16_t* p3 = W0b + (size_t)__builtin_amdgcn_readfirstlane(s_idx[t + 3]) * D0;
    bf16x2 w0 = *reinterpret_cast<const bf16x2*>(p0 + col);
    bf16x2 w1 = *reinterpret_cast<const bf16x2*>(p1 + col);
    bf16x2 w2 = *reinterpret_cast<const bf16x2*>(p2 + col);
    bf16x2 w3 = *reinterpret_cast<const bf16x2*>(p3 + col);
    c0 += (float)w0[0]; c1 += (float)w0[1];
    d0_ += (float)w1[0]; d1_ += (float)w1[1];
    e0 += (float)w2[0]; e1 += (float)w2[1];
    f0 += (float)w3[0]; f1 += (float)w3[1];
  }
  for (; t < n; ++t) {
    const bf16_t* p = W0b + (size_t)__builtin_amdgcn_readfirstlane(s_idx[t]) * D0;
    bf16x2 w = *reinterpret_cast<const bf16x2*>(p + col);
    c0 += (float)w[0]; c1 += (float)w[1];
  }
  float2 o;
  o.x = ((c0 + d0_) + (e0 + f0)) + b0[col];
  o.y = ((c1 + d1_) + (e1 + f1)) + b0[col + 1];
  *reinterpret_cast<float2*>(h0 + (size_t)d * D0 + col) = o;
}

// ---------------------------------------------------------------------------
// Kernel 4: FUSED build_H + gemm1(relu) + gemm2 + pair-dot — R4 design with
// the barrier count slashed 35 -> 6. R5 measured the BK=64 version at
// 56.6us with MfmaUtil 14% (barrier-serialized at 1 block/CU; R6 proved
// 2-blocks/CU at BR=32 doesn't fix it). Here: BK=512, 2 chunks, single-
// buffered 64KB A-tile, 256 MFMA/wave between barriers.
// LDS 129KB -> 1 block/CU (grid 256 = 1/CU anyway).
// A-tile swizzle: 16B-granule index g ^= (row&7) on BOTH ds_write (staging
// is reg-staged, so write side is free to swizzle) and read — spreads the
// row-stride-1024B pattern across all 8 bank-quads (G4 fix).
// C/D: lane l, reg r -> row = m*16 + 4*(l>>4) + r, col = l&15.
// ---------------------------------------------------------------------------
__global__ __launch_bounds__(512, 2) void k_fused(
    const float* __restrict__ h0, const int* __restrict__ pairs,
    const float* __restrict__ conc, const float* __restrict__ W0last,
    const float* __restrict__ b1v, const bf16_t* __restrict__ W1T,
    const float* __restrict__ b2v, const bf16_t* __restrict__ W2T,
    float* __restrict__ out)
{
  __shared__ bf16_t smemA[BR * 512];   // 64 KB, [row][512k], granule-swizzled
  __shared__ bf16_t smemH1[BR * D1];   // 64 KB, [row][512], granule-swizzled
  __shared__ float red[8][32];

  const int tid = threadIdx.x;
  const int w = tid >> 6;        // wave 0..7 -> 64-col strip of layer-1
  const int lane = tid & 63;
  const int fr = lane & 15;
  const int q = lane >> 4;       // 0..3
  const int row0 = blockIdx.x * BR;

  // --- staging role: thread covers row srow, granules sg, sg+8, .., sg+56 ---
  const int srow = tid >> 3;          // 0..63
  const int sg = tid & 7;
  const int gr = row0 + srow;
  const int drug = pairs[gr];
  const float c = conc[3 * (gr >> 1) + 1 + (gr & 1)];
  const float* hrow = h0 + (size_t)drug * D0;

  f32x4 acc[4][4] = {};

  // stage chunk ch (512 k) of H = relu(h0 + c*wl) into swizzled smemA
  auto stageA = [&](int ch) {
    const int kbase = ch * 512;
#pragma unroll
    for (int j = 0; j < 8; ++j) {
      const int g = sg + 8 * j;            // granule 0..63 (8 bf16 each)
      const int k = g * 8;
      f32x8 h = *reinterpret_cast<const f32x8*>(hrow + kbase + k);
      f32x8 wl = *reinterpret_cast<const f32x8*>(W0last + kbase + k);
      bf16x8 o;
#pragma unroll
      for (int e = 0; e < 8; ++e) o[e] = (bf16_t)fmaxf(h[e] + c * wl[e], 0.f);
      const int gs = g ^ (srow & 7);
      *reinterpret_cast<bf16x8*>((char*)smemA + srow * 1024 + gs * 16) = o;
    }
  };

  // compute 256 MFMA/wave over chunk ch; B direct from global (W1T L2-hot)
  auto computeCh = [&](int ch) {
#pragma unroll 4
    for (int kk = 0; kk < 16; ++kk) {      // 32-k steps within the chunk
      bf16x8 b[4], a[4];
#pragma unroll
      for (int n = 0; n < 4; ++n)
        b[n] = *reinterpret_cast<const bf16x8*>(
            W1T + (size_t)(w * 64 + n * 16 + fr) * D0 + ch * 512 + kk * 32 + q * 8);
#pragma unroll
      for (int m = 0; m < 4; ++m) {
        const int row = m * 16 + fr;
        const int gs = (kk * 4 + q) ^ (row & 7);
        a[m] = *reinterpret_cast<const bf16x8*>((const char*)smemA + row * 1024 + gs * 16);
      }
#pragma unroll
      for (int m = 0; m < 4; ++m)
#pragma unroll
        for (int n = 0; n < 4; ++n)
          acc[m][n] = __builtin_amdgcn_mfma_f32_16x16x32_bf16(a[m], b[n], acc[m][n], 0, 0, 0);
    }
  };

  stageA(0);
  __syncthreads();
  computeCh(0);
  __syncthreads();      // all waves done reading smemA chunk 0
  stageA(1);
  __syncthreads();
  computeCh(1);

  // --- epilogue: relu(acc + b1) -> bf16 H1 tile in LDS (granule-swizzled) ---
#pragma unroll
  for (int m = 0; m < 4; ++m)
#pragma unroll
    for (int n = 0; n < 4; ++n) {
      const int col = w * 64 + n * 16 + fr;
      const float bb = b1v[col];
#pragma unroll
      for (int r = 0; r < 4; ++r) {
        const int row = m * 16 + 4 * q + r;
        const float v = fmaxf(acc[m][n][r] + bb, 0.f);
        const uint32_t byte = row * 1024 + ((uint32_t)(col * 2) ^ ((row & 7) << 4));
        *reinterpret_cast<bf16_t*>((char*)smemH1 + byte) = (bf16_t)v;
      }
    }
  __syncthreads();

  // --- phase 2: layer-2 gemm, wave w -> out cols w*16..w*16+15 ---
  f32x4 acc2[4] = {};
#pragma unroll 4
  for (int kk = 0; kk < 16; ++kk) {
    const bf16x8 b2 = *reinterpret_cast<const bf16x8*>(
        W2T + (size_t)(w * 16 + fr) * D1 + kk * 32 + q * 8);
    bf16x8 a2[4];
#pragma unroll
    for (int m = 0; m < 4; ++m) {
      const int row = m * 16 + fr;
      const uint32_t byte = row * 1024 + ((uint32_t)(kk * 64 + q * 16) ^ ((row & 7) << 4));
      a2[m] = *reinterpret_cast<const bf16x8*>((const char*)smemH1 + byte);
    }
#pragma unroll
    for (int m = 0; m < 4; ++m)
      acc2[m] = __builtin_amdgcn_mfma_f32_16x16x32_bf16(a2[m], b2, acc2[m], 0, 0, 0);
  }

  // --- pair-dot epilogue: rows 4q+{0,1} and {2,3} within each m-tile pair ---
  const float bb2 = b2v[w * 16 + fr];
#pragma unroll
  for (int m = 0; m < 4; ++m) {
    const float v0 = acc2[m][0] + bb2;
    const float v1 = acc2[m][1] + bb2;
    const float v2 = acc2[m][2] + bb2;
    const float v3 = acc2[m][3] + bb2;
    float pa = v0 * v1, pb = v2 * v3;
#pragma unroll
    for (int off = 8; off >= 1; off >>= 1) {
      pa += __shfl_xor(pa, off);
      pb += __shfl_xor(pb, off);
    }
    if (fr == 0) {
      red[w][m * 8 + 2 * q] = pa;
      red[w][m * 8 + 2 * q + 1] = pb;
    }
  }
  __syncthreads();
  if (tid < 32) {
    float s = 0.f;
#pragma unroll
    for (int ww = 0; ww < 8; ++ww) s += red[ww][tid];
    out[blockIdx.x * 32 + tid] = s;
  }
}

extern "C" void kernel_launch(void* const* d_in, const int* in_sizes, int n_in,
                              void* d_out, int out_size, void* d_ws, size_t ws_size,
                              hipStream_t stream) {
  const float* table = (const float*)d_in[0];
  const int*   pairs = (const int*)d_in[1];
  const float* conc  = (const float*)d_in[2];
  const float* W0    = (const float*)d_in[3];
  const float* b0    = (const float*)d_in[4];
  const float* W1    = (const float*)d_in[5];
  const float* b1    = (const float*)d_in[6];
  const float* W2    = (const float*)d_in[7];
  const float* b2    = (const float*)d_in[8];
  float* out = (float*)d_out;

  // Workspace (16B-aligned, ~60.5 MB):
  char* ws = (char*)d_ws;
  float*  h0  = (float*)ws;  ws += (size_t)N_DRUGS * D0 * sizeof(float);    // 17.2 MB
  bf16_t* W0b = (bf16_t*)ws; ws += (size_t)N_PROT * D0 * sizeof(bf16_t);    // 38.9 MB
  bf16_t* W1T = (bf16_t*)ws; ws += (size_t)D1 * D0 * sizeof(bf16_t);        //  1.0 MB
  bf16_t* W2T = (bf16_t*)ws; ws += (size_t)D2 * D1 * sizeof(bf16_t);        //  0.13 MB
  int* g_idx = (int*)ws;     ws += (size_t)N_DRUGS * MAXNNZ * sizeof(int);  //  3.2 MB
  int* g_cnt = (int*)ws;     ws += (size_t)N_DRUGS * sizeof(int);           // 16.8 KB

  k_convert<<<2048, 256, 0, stream>>>(W0, W1, W2, W0b, W1T, W2T);
  k_scan<<<N_DRUGS, 256, 0, stream>>>((const uint32_t*)table, g_cnt, g_idx);
  k_gather<<<N_DRUGS * NCHUNK, 64, 0, stream>>>(W0b, g_cnt, g_idx, b0, h0);
  k_fused<<<NROWS / BR, 512, 0, stream>>>(h0, pairs, conc, W0 + (size_t)N_PROT * D0,
                                          b1, W1T, b2, W2T, out);
}